// Round 5
// baseline (291.457 us; speedup 1.0000x reference)
//
#include <hip/hip_runtime.h>

// B=8, N=2048, DIN=DOUT=128, DA=2, NEG_SLOPE=0.2
// out[b,i,:] = sum_j mask[b,i,j]*w[b,j]*xv[b,j,:] / sum_j mask[b,i,j]*w[b,j]
//   w[b,j]  = exp( leaky(x@Wc[0])*Wcat[2] + leaky(x@Wc[1])*Wcat[3] )   (lr_row cancels in softmax)
//   xv      = x @ Wx^T + bx

typedef __bf16 bf16x8 __attribute__((ext_vector_type(8)));
typedef __bf16 bf16x4 __attribute__((ext_vector_type(4)));
typedef float  f32x4  __attribute__((ext_vector_type(4)));
typedef int    i32x4  __attribute__((ext_vector_type(4)));

#define MFMA_BF16(a, b, c) __builtin_amdgcn_mfma_f32_16x16x32_bf16((a), (b), (c), 0, 0, 0)

static __device__ __forceinline__ bf16x8 cvt8(f32x4 a, f32x4 b) {
  bf16x8 r;
  r[0] = (__bf16)a[0]; r[1] = (__bf16)a[1]; r[2] = (__bf16)a[2]; r[3] = (__bf16)a[3];
  r[4] = (__bf16)b[0]; r[5] = (__bf16)b[1]; r[6] = (__bf16)b[2]; r[7] = (__bf16)b[3];
  return r;
}

// ---------------------------------------------------------------------------
// Kernel A: per (b, 64 k-rows): compute w[k] and u[k][c] = w[k]*(xv[k][c]),
// write u pre-swizzled in mfma_16x16x32 B-fragment order:
//   elem(b,t,n,lane,j) = u[k = t*32 + (lane>>4)*8 + j][c = n*16 + (lane&15)]
//   at flat index (((b*64+t)*8+n)*64+lane)*8+j
// ---------------------------------------------------------------------------
__global__ __launch_bounds__(256) void prep_kernel(
    const float* __restrict__ x, const float* __restrict__ Wc,
    const float* __restrict__ Wcat, const float* __restrict__ Wx,
    const float* __restrict__ bx, __bf16* __restrict__ u,
    __bf16* __restrict__ wcol)
{
  __shared__ __bf16 lds[8192];  // 16 KB: 2 t-steps x 8 tiles x 64 lanes x 8
  const int blk = blockIdx.x;            // 256 blocks
  const int b = blk >> 5, mt = blk & 31; // 32 blocks/batch, 64 rows each
  const int wv = threadIdx.x >> 6, lane = threadIdx.x & 63;
  const int np = lane & 15, G = lane >> 4;
  const int r0 = mt * 64 + wv * 16;      // wave's 16 k-rows

  // A-fragments: x rows (f32 -> bf16). lane np = row, k = kk*32 + G*8 + j
  const float* xp = x + ((size_t)(b * 2048 + r0 + np)) * 128 + G * 8;
  bf16x8 af[4];
#pragma unroll
  for (int kk = 0; kk < 4; ++kk) {
    f32x4 x0 = *(const f32x4*)(xp + kk * 32);
    f32x4 x1 = *(const f32x4*)(xp + kk * 32 + 4);
    af[kk] = cvt8(x0, x1);
  }

  f32x4 acc[8], accC;
#pragma unroll
  for (int n = 0; n < 8; ++n) { acc[n][0] = 0.f; acc[n][1] = 0.f; acc[n][2] = 0.f; acc[n][3] = 0.f; }
  accC[0] = accC[1] = accC[2] = accC[3] = 0.f;

  // xv = x @ Wx^T : B-frag lane reads Wx[n*16+np][k] (row-major, contiguous k)
#pragma unroll
  for (int n = 0; n < 8; ++n) {
    const float* wp = Wx + (n * 16 + np) * 128 + G * 8;
#pragma unroll
    for (int kk = 0; kk < 4; ++kk) {
      f32x4 w0 = *(const f32x4*)(wp + kk * 32);
      f32x4 w1 = *(const f32x4*)(wp + kk * 32 + 4);
      acc[n] = MFMA_BF16(af[kk], cvt8(w0, w1), acc[n]);
    }
  }
  // Wc tile: cols 0,1 = x . Wc[0], x . Wc[1]
#pragma unroll
  for (int kk = 0; kk < 4; ++kk) {
    bf16x8 bf;
    if (np < 2) {
      const float* cp = Wc + np * 128 + kk * 32 + G * 8;
      f32x4 c0 = *(const f32x4*)cp;
      f32x4 c1 = *(const f32x4*)(cp + 4);
      bf = cvt8(c0, c1);
    } else {
#pragma unroll
      for (int j = 0; j < 8; ++j) bf[j] = (__bf16)0.0f;
    }
    accC = MFMA_BF16(af[kk], bf, accC);
  }

  // epilogue: w = exp(leaky(c0)*a2_0 + leaky(c1)*a2_1), per D-row (= 4G + r)
  const float a20 = Wcat[2], a21 = Wcat[3];
  float wexp[4];
#pragma unroll
  for (int r = 0; r < 4; ++r) {
    float c0 = __shfl(accC[r], lane & 48);        // col 0 of Wc tile
    float c1 = __shfl(accC[r], (lane & 48) | 1);  // col 1
    c0 = c0 > 0.f ? c0 : 0.2f * c0;
    c1 = c1 > 0.f ? c1 : 0.2f * c1;
    wexp[r] = __expf(c0 * a20 + c1 * a21);
  }
  if (np == 0) {  // lanes 0,16,32,48 write w for rows r0+4G+{0..3}
    bf16x4 w4;
#pragma unroll
    for (int r = 0; r < 4; ++r) w4[r] = (__bf16)wexp[r];
    *(bf16x4*)(wcol + (size_t)b * 2048 + r0 + 4 * G) = w4;
  }

  // scatter u values into fragment order via LDS, then linear copy-out.
  // k_in_block = wv*16 + 4G + r  ->  t_rel = wv>>1, g_store = (wv&1)*2 + (G>>1),
  // j = (G&1)*4 + r  (4 consecutive j for r=0..3 -> one b64 write)
  const int t_rel = wv >> 1;
  const int g_store = (wv & 1) * 2 + (G >> 1);
  const int j0 = (G & 1) * 4;
#pragma unroll
  for (int n = 0; n < 8; ++n) {
    float bxv = bx[n * 16 + np];
    bf16x4 v;
#pragma unroll
    for (int r = 0; r < 4; ++r) v[r] = (__bf16)(wexp[r] * (acc[n][r] + bxv));
    *(bf16x4*)(&lds[(t_rel * 8 + n) * 512 + g_store * 128 + np * 8 + j0]) = v;
  }
  __syncthreads();
  __bf16* dst = u + ((size_t)(b * 64 + mt * 2)) * 4096;
#pragma unroll
  for (int it = 0; it < 4; ++it) {
    int s = it * 256 + threadIdx.x;
    ((i32x4*)dst)[s] = ((const i32x4*)lds)[s];  // 16 KB, coalesced
  }
}

// ---------------------------------------------------------------------------
// Kernel B v5: out = (mask .* w) @ xv / (mask @ w), batched MFMA GEMM.
// Column-split waves (each wave: 2 n-tiles + own denominator, full K).
// 4-deep register mask ring + 2-deep u/w. v4 BUG FIX: COMP(slot) must
// precede LOADM(slot, t+4) — same registers; v4 overwrote the mask before
// consuming it (absmax 9e-2). Order is now consume -> refill.
// No LDS, no barriers in the K loop.
// ---------------------------------------------------------------------------
__global__ __launch_bounds__(256) void attn_kernel(
    const int* __restrict__ mask, const __bf16* __restrict__ u,
    const __bf16* __restrict__ wcol, float* __restrict__ out)
{
  const int b = blockIdx.x & 7, rt = blockIdx.x >> 3;  // 8 x 128
  const int wv = threadIdx.x >> 6, lane = threadIdx.x & 63;
  const int np = lane & 15, G = lane >> 4;
  const int row0 = rt * 16;
  const long long N = 2048;
  const int n0 = wv * 2, n1 = n0 + 1;

  const int* mp = mask + ((size_t)b * N + row0 + np) * N + G * 8;
  const __bf16* up = u + (size_t)b * 64 * 4096 + lane * 8;  // + t*4096 + n*512
  const __bf16* wp = wcol + (size_t)b * 2048 + G * 8;       // + t*32

  f32x4 accN0, accN1, accD;
  accN0[0]=accN0[1]=accN0[2]=accN0[3]=0.f;
  accN1[0]=accN1[1]=accN1[2]=accN1[3]=0.f;
  accD[0]=accD[1]=accD[2]=accD[3]=0.f;

  // 4-deep mask ring (slot = t & 3), 2-deep u/w (parity A/B)
  i32x4 M0_0, M1_0, M0_1, M1_1, M0_2, M1_2, M0_3, M1_3;
  bf16x8 u0A, u1A, wA, u0B, u1B, wB;

#define LOADM(s, t)                                   \
  do {                                                \
    const int* p = mp + (t) * 32;                     \
    M0_##s = *(const i32x4*)p;                        \
    M1_##s = *(const i32x4*)(p + 4);                  \
  } while (0)

#define LOADU(buf, t)                                 \
  do {                                                \
    const __bf16* p = up + (size_t)(t) * 4096;        \
    u0##buf = *(const bf16x8*)(p + n0 * 512);         \
    u1##buf = *(const bf16x8*)(p + n1 * 512);         \
    w##buf = *(const bf16x8*)(wp + (t) * 32);         \
  } while (0)

#define COMP(s, buf)                                                     \
  do {                                                                   \
    const __bf16 ONE = (__bf16)1.0f, ZER = (__bf16)0.0f;                 \
    bf16x8 af;                                                           \
    af[0] = M0_##s[0] ? ONE : ZER; af[1] = M0_##s[1] ? ONE : ZER;        \
    af[2] = M0_##s[2] ? ONE : ZER; af[3] = M0_##s[3] ? ONE : ZER;        \
    af[4] = M1_##s[0] ? ONE : ZER; af[5] = M1_##s[1] ? ONE : ZER;        \
    af[6] = M1_##s[2] ? ONE : ZER; af[7] = M1_##s[3] ? ONE : ZER;        \
    bf16x8 wfrag;                                                        \
    _Pragma("unroll")                                                    \
    for (int j = 0; j < 8; ++j) wfrag[j] = (np == 0) ? w##buf[j] : ZER;  \
    accN0 = MFMA_BF16(af, u0##buf, accN0);                               \
    accN1 = MFMA_BF16(af, u1##buf, accN1);                               \
    accD  = MFMA_BF16(af, wfrag, accD);                                  \
  } while (0)

  // prologue: mask slots 0-3 (t=0..3), u/w for t=0 (A), t=1 (B)
  LOADM(0, 0); LOADM(1, 1); LOADM(2, 2); LOADM(3, 3);
  LOADU(A, 0); LOADU(B, 1);

  // main loop: consume slot (t&3), THEN refill it with mask for t+4;
  // u/w (L2-resident) refill 2 steps ahead right after consumption.
  for (int t = 0; t < 60; t += 4) {
    COMP(0, A); LOADM(0, t + 4); LOADU(A, t + 2);
    COMP(1, B); LOADM(1, t + 5); LOADU(B, t + 3);
    COMP(2, A); LOADM(2, t + 6); LOADU(A, t + 4);
    COMP(3, B); LOADM(3, t + 7); LOADU(B, t + 5);
  }
  // tail: t = 60..63 (mask slots hold 60..63 from the last iteration)
  COMP(0, A); LOADU(A, 62);
  COMP(1, B); LOADU(B, 63);
  COMP(2, A);
  COMP(3, B);
#undef LOADM
#undef LOADU
#undef COMP

  // epilogue: D row i = 4G+r, col = n*16+np; denom lives in col 0 (np==0)
#pragma unroll
  for (int r = 0; r < 4; ++r) {
    float den = __shfl(accD[r], lane & 48);
    float inv = 1.0f / den;
    float* op = out + ((size_t)b * N + row0 + 4 * G + r) * 128 + np;
    op[n0 * 16] = accN0[r] * inv;
    op[n1 * 16] = accN1[r] * inv;
  }
}

extern "C" void kernel_launch(void* const* d_in, const int* in_sizes, int n_in,
                              void* d_out, int out_size, void* d_ws, size_t ws_size,
                              hipStream_t stream) {
  const float* x    = (const float*)d_in[0];
  const int*   mask = (const int*)d_in[1];
  // d_in[2] = Wr : unused (lr_row cancels in softmax over j)
  const float* Wc   = (const float*)d_in[3];
  const float* Wcat = (const float*)d_in[4];
  const float* Wx   = (const float*)d_in[5];
  const float* bx   = (const float*)d_in[6];
  float* out = (float*)d_out;

  // workspace: u (8*64*4096 bf16 = 4 MB) + wcol (8*2048 bf16 = 32 KB)
  const size_t U_BYTES = (size_t)8 * 64 * 4096 * 2;
  if (ws_size < U_BYTES + 8 * 2048 * 2) return;  // insufficient scratch
  __bf16* u    = (__bf16*)d_ws;
  __bf16* wcol = (__bf16*)((char*)d_ws + U_BYTES);

  prep_kernel<<<256, 256, 0, stream>>>(x, Wc, Wcat, Wx, bx, u, wcol);
  attn_kernel<<<1024, 256, 0, stream>>>(mask, u, wcol, out);
}

// Round 6
// 227.493 us; speedup vs baseline: 1.2812x; 1.2812x over previous
//
#include <hip/hip_runtime.h>

// B=8, N=2048, DIN=DOUT=128, DA=2, NEG_SLOPE=0.2
// out[b,i,:] = sum_j mask[b,i,j]*w[b,j]*xv[b,j,:] / sum_j mask[b,i,j]*w[b,j]
//   w[b,j]  = exp( leaky(x@Wc[0])*Wcat[2] + leaky(x@Wc[1])*Wcat[3] )  (lr_row cancels)
//   xv      = x @ Wx^T + bx
// u layout: 9 B-fragment tiles per 32-k t-step; tile 8 col0 = w (denominator).

typedef __bf16 bf16x8 __attribute__((ext_vector_type(8)));
typedef __bf16 bf16x4 __attribute__((ext_vector_type(4)));
typedef float  f32x4  __attribute__((ext_vector_type(4)));
typedef int    i32x4  __attribute__((ext_vector_type(4)));
typedef unsigned int u32;

#define MFMA_BF16(a, b, c) __builtin_amdgcn_mfma_f32_16x16x32_bf16((a), (b), (c), 0, 0, 0)

// async global->LDS, 16B/lane; dest = lds_base + lane*16 (wave-uniform base)
#define GLOAD_LDS16(gp, lp)                                                     \
  __builtin_amdgcn_global_load_lds(                                             \
      (const __attribute__((address_space(1))) void*)(gp),                      \
      (__attribute__((address_space(3))) void*)(lp), 16, 0, 0)

static __device__ __forceinline__ bf16x8 cvt8(f32x4 a, f32x4 b) {
  bf16x8 r;
  r[0] = (__bf16)a[0]; r[1] = (__bf16)a[1]; r[2] = (__bf16)a[2]; r[3] = (__bf16)a[3];
  r[4] = (__bf16)b[0]; r[5] = (__bf16)b[1]; r[6] = (__bf16)b[2]; r[7] = (__bf16)b[3];
  return r;
}

// ---------------------------------------------------------------------------
// Kernel A: per (b, 64 k-rows): compute w[k], xv[k][c]; write u pre-swizzled
// in mfma_16x16x32 B-fragment order, 9 tiles per t-step:
//   n<8: elem(b,t,n,lane,j) = w[k]*xv[k][n*16+np],  k = t*32+(lane>>4)*8+j
//   n=8: elem = (np==0) ? w[k] : 0    (denominator column)
// flat index (((b*64+t)*9+n)*64+lane)*8+j
// ---------------------------------------------------------------------------
__global__ __launch_bounds__(256) void prep_kernel(
    const float* __restrict__ x, const float* __restrict__ Wc,
    const float* __restrict__ Wcat, const float* __restrict__ Wx,
    const float* __restrict__ bx, __bf16* __restrict__ u)
{
  __shared__ __bf16 lds[9216];  // 18 KB: 2 t-steps x 9 tiles x 64 lanes x 8
  const int blk = blockIdx.x;            // 256 blocks
  const int b = blk >> 5, mt = blk & 31; // 32 blocks/batch, 64 rows each
  const int wv = threadIdx.x >> 6, lane = threadIdx.x & 63;
  const int np = lane & 15, G = lane >> 4;
  const int r0 = mt * 64 + wv * 16;      // wave's 16 k-rows

  // A-fragments: x rows (f32 -> bf16). lane np = row, k = kk*32 + G*8 + j
  const float* xp = x + ((size_t)(b * 2048 + r0 + np)) * 128 + G * 8;
  bf16x8 af[4];
#pragma unroll
  for (int kk = 0; kk < 4; ++kk) {
    f32x4 x0 = *(const f32x4*)(xp + kk * 32);
    f32x4 x1 = *(const f32x4*)(xp + kk * 32 + 4);
    af[kk] = cvt8(x0, x1);
  }

  f32x4 acc[8], accC;
#pragma unroll
  for (int n = 0; n < 8; ++n) { acc[n][0] = 0.f; acc[n][1] = 0.f; acc[n][2] = 0.f; acc[n][3] = 0.f; }
  accC[0] = accC[1] = accC[2] = accC[3] = 0.f;

  // xv = x @ Wx^T : B-frag lane reads Wx[n*16+np][k] (row-major, contiguous k)
#pragma unroll
  for (int n = 0; n < 8; ++n) {
    const float* wp = Wx + (n * 16 + np) * 128 + G * 8;
#pragma unroll
    for (int kk = 0; kk < 4; ++kk) {
      f32x4 w0 = *(const f32x4*)(wp + kk * 32);
      f32x4 w1 = *(const f32x4*)(wp + kk * 32 + 4);
      acc[n] = MFMA_BF16(af[kk], cvt8(w0, w1), acc[n]);
    }
  }
  // Wc tile: cols 0,1 = x . Wc[0], x . Wc[1]
#pragma unroll
  for (int kk = 0; kk < 4; ++kk) {
    bf16x8 bf;
    if (np < 2) {
      const float* cp = Wc + np * 128 + kk * 32 + G * 8;
      f32x4 c0 = *(const f32x4*)cp;
      f32x4 c1 = *(const f32x4*)(cp + 4);
      bf = cvt8(c0, c1);
    } else {
#pragma unroll
      for (int j = 0; j < 8; ++j) bf[j] = (__bf16)0.0f;
    }
    accC = MFMA_BF16(af[kk], bf, accC);
  }

  // epilogue: w = exp(leaky(c0)*a2_0 + leaky(c1)*a2_1), per D-row (= 4G + r)
  const float a20 = Wcat[2], a21 = Wcat[3];
  float wexp[4];
#pragma unroll
  for (int r = 0; r < 4; ++r) {
    float c0 = __shfl(accC[r], lane & 48);        // col 0 of Wc tile
    float c1 = __shfl(accC[r], (lane & 48) | 1);  // col 1
    c0 = c0 > 0.f ? c0 : 0.2f * c0;
    c1 = c1 > 0.f ? c1 : 0.2f * c1;
    wexp[r] = __expf(c0 * a20 + c1 * a21);
  }

  // scatter into fragment order via LDS, then linear copy-out.
  // k_in_block = wv*16 + 4G + r -> t_rel = wv>>1, g_store = (wv&1)*2 + (G>>1),
  // j = (G&1)*4 + r  (4 consecutive j -> one b64 write)
  const int t_rel = wv >> 1;
  const int g_store = (wv & 1) * 2 + (G >> 1);
  const int j0 = (G & 1) * 4;
#pragma unroll
  for (int n = 0; n < 8; ++n) {
    float bxv = bx[n * 16 + np];
    bf16x4 v;
#pragma unroll
    for (int r = 0; r < 4; ++r) v[r] = (__bf16)(wexp[r] * (acc[n][r] + bxv));
    *(bf16x4*)(&lds[(t_rel * 9 + n) * 512 + g_store * 128 + np * 8 + j0]) = v;
  }
  {  // tile 8: denominator column (np==0 lanes carry w, others 0)
    bf16x4 v8;
#pragma unroll
    for (int r = 0; r < 4; ++r) v8[r] = (np == 0) ? (__bf16)wexp[r] : (__bf16)0.0f;
    *(bf16x4*)(&lds[(t_rel * 9 + 8) * 512 + g_store * 128 + np * 8 + j0]) = v8;
  }
  __syncthreads();
  __bf16* dst = u + ((size_t)(b * 64 + mt * 2)) * 9 * 512;
  for (int s = threadIdx.x; s < 1152; s += 256)  // 18 KB, coalesced
    ((i32x4*)dst)[s] = ((const i32x4*)lds)[s];
}

// ---------------------------------------------------------------------------
// Kernel B v6: 2-phase global_load_lds pipeline (the only structure hipcc
// preserves — v1/v3/v5 register pipelines all collapsed to serial chains).
// Block = 32 rows, 4 waves; wave = 2 m-tiles x (2 n-tiles + denom tile).
// K-loop: 16 iters of BK=128; double-buffered LDS mask tile [32][128] i32,
// staged via global_load_lds with XOR-swizzled SOURCE addresses
// (byte ^= ((row&7)<<4), m173/m214 pattern) so swizzled ds_read_b128 is
// ~conflict-free. One __syncthreads (compiler vmcnt drain) per iter.
// ---------------------------------------------------------------------------
__global__ __launch_bounds__(256) void attn_kernel(
    const int* __restrict__ mask, const __bf16* __restrict__ u,
    float* __restrict__ out)
{
  __shared__ int smask[2 * 4096];  // 2 bufs x 32 rows x 128 cols, 32 KB
  const int b = blockIdx.x & 7, rt = blockIdx.x >> 3;  // 8 x 64
  const int wv = threadIdx.x >> 6, lane = threadIdx.x & 63;
  const int np = lane & 15, G = lane >> 4;
  const int row0 = rt * 32;
  const int n0 = wv * 2, n1 = n0 + 1;
  const int swz = (np & 7) << 2;   // read-side swizzle, dword units
  const int hl = lane >> 5, cb = (lane & 31) * 16;  // staging lane coords

  const char* gbase = (const char*)(mask + ((size_t)b * 2048 + row0) * 2048);
  const __bf16* up = u + (size_t)b * 64 * 9 * 512 + lane * 8;

  f32x4 acc[2][3];
#pragma unroll
  for (int mi = 0; mi < 2; ++mi)
#pragma unroll
    for (int n = 0; n < 3; ++n) { acc[mi][n][0] = 0.f; acc[mi][n][1] = 0.f; acc[mi][n][2] = 0.f; acc[mi][n][3] = 0.f; }

  // stage K-chunk `it` into buffer nb: 4 instrs/wave, 2 rows each.
  // source byte pre-swizzled so LDS[row][c] = mask[row][c ^ ((row&7)<<4)].
#define STAGE(it, nb)                                                          \
  do {                                                                         \
    char* lbase = (char*)smask + (nb) * 16384 + wv * 4096;                     \
    _Pragma("unroll")                                                          \
    for (int i = 0; i < 4; ++i) {                                              \
      int lr = wv * 8 + i * 2 + hl;                                            \
      const char* gp = gbase + (size_t)lr * 8192 + (it) * 512 +                \
                       (cb ^ (((i * 2 + hl) & 7) << 4));                       \
      GLOAD_LDS16(gp, lbase + i * 1024);                                       \
    }                                                                          \
  } while (0)

  STAGE(0, 0);
  __syncthreads();

  for (int it = 0; it < 16; ++it) {
    if (it < 15) STAGE(it + 1, (it + 1) & 1);
    const u32* cur = (const u32*)smask + (it & 1) * 4096;
#pragma unroll
    for (int tk = 0; tk < 4; ++tk) {
      const int t = it * 4 + tk;
      const __bf16* ut = up + (size_t)(t * 9) * 512;
      bf16x8 U0 = *(const bf16x8*)(ut + n0 * 512);
      bf16x8 U1 = *(const bf16x8*)(ut + n1 * 512);
      bf16x8 UD = *(const bf16x8*)(ut + 8 * 512);
      const int X = tk * 32 + G * 8;
#pragma unroll
      for (int mi = 0; mi < 2; ++mi) {
        const u32* rp = cur + (mi * 16 + np) * 128;
        i32x4 ma = *(const i32x4*)(rp + (X ^ swz));
        i32x4 mb = *(const i32x4*)(rp + ((X + 4) ^ swz));
        union { u32 w[4]; bf16x8 v; } A;
        A.w[0] = (ma[0] ? 0x3F80u : 0u) | (ma[1] ? 0x3F800000u : 0u);
        A.w[1] = (ma[2] ? 0x3F80u : 0u) | (ma[3] ? 0x3F800000u : 0u);
        A.w[2] = (mb[0] ? 0x3F80u : 0u) | (mb[1] ? 0x3F800000u : 0u);
        A.w[3] = (mb[2] ? 0x3F80u : 0u) | (mb[3] ? 0x3F800000u : 0u);
        acc[mi][0] = MFMA_BF16(A.v, U0, acc[mi][0]);
        acc[mi][1] = MFMA_BF16(A.v, U1, acc[mi][1]);
        acc[mi][2] = MFMA_BF16(A.v, UD, acc[mi][2]);
      }
    }
    __syncthreads();  // drains staged loads (vmcnt) + frees cur buffer
  }
#undef STAGE

  // epilogue: D row = mi*16 + 4G + r, cols n*16+np; denom = col0 of tile 8
#pragma unroll
  for (int mi = 0; mi < 2; ++mi) {
#pragma unroll
    for (int r = 0; r < 4; ++r) {
      float den = __shfl(acc[mi][2][r], lane & 48);
      float inv = 1.0f / den;
      float* op = out + ((size_t)b * 2048 + row0 + mi * 16 + 4 * G + r) * 128 + np;
      op[n0 * 16] = acc[mi][0][r] * inv;
      op[n1 * 16] = acc[mi][1][r] * inv;
    }
  }
}

extern "C" void kernel_launch(void* const* d_in, const int* in_sizes, int n_in,
                              void* d_out, int out_size, void* d_ws, size_t ws_size,
                              hipStream_t stream) {
  const float* x    = (const float*)d_in[0];
  const int*   mask = (const int*)d_in[1];
  // d_in[2] = Wr : unused (lr_row cancels in softmax over j)
  const float* Wc   = (const float*)d_in[3];
  const float* Wcat = (const float*)d_in[4];
  const float* Wx   = (const float*)d_in[5];
  const float* bx   = (const float*)d_in[6];
  float* out = (float*)d_out;

  // workspace: u = 8 b x 64 t x 9 tiles x 512 bf16 = 4.72 MB
  const size_t U_BYTES = (size_t)8 * 64 * 9 * 512 * 2;
  if (ws_size < U_BYTES) return;  // insufficient scratch
  __bf16* u = (__bf16*)d_ws;

  prep_kernel<<<256, 256, 0, stream>>>(x, Wc, Wcat, Wx, bx, u);
  attn_kernel<<<512, 256, 0, stream>>>(mask, u, out);
}

// Round 7
// 226.398 us; speedup vs baseline: 1.2874x; 1.0048x over previous
//
#include <hip/hip_runtime.h>

// B=8, N=2048, DIN=DOUT=128, DA=2, NEG_SLOPE=0.2
// out[b,i,:] = sum_j mask[b,i,j]*w[b,j]*xv[b,j,:] / sum_j mask[b,i,j]*w[b,j]
//   w[b,j]  = exp( leaky(x@Wc[0])*Wcat[2] + leaky(x@Wc[1])*Wcat[3] )  (lr_row cancels)
//   xv      = x @ Wx^T + bx
// u layout: 9 B-fragment tiles per 32-k t-step; tile 8 col0 = w (denominator).

typedef __bf16 bf16x8 __attribute__((ext_vector_type(8)));
typedef __bf16 bf16x4 __attribute__((ext_vector_type(4)));
typedef float  f32x4  __attribute__((ext_vector_type(4)));
typedef int    i32x4  __attribute__((ext_vector_type(4)));
typedef unsigned int u32;

#define MFMA_BF16(a, b, c) __builtin_amdgcn_mfma_f32_16x16x32_bf16((a), (b), (c), 0, 0, 0)

// async global->LDS, 16B/lane; dest = lds_base + lane*16 (wave-uniform base)
#define GLOAD_LDS16(gp, lp)                                                     \
  __builtin_amdgcn_global_load_lds(                                             \
      (const __attribute__((address_space(1))) void*)(gp),                      \
      (__attribute__((address_space(3))) void*)(lp), 16, 0, 0)

static __device__ __forceinline__ bf16x8 cvt8(f32x4 a, f32x4 b) {
  bf16x8 r;
  r[0] = (__bf16)a[0]; r[1] = (__bf16)a[1]; r[2] = (__bf16)a[2]; r[3] = (__bf16)a[3];
  r[4] = (__bf16)b[0]; r[5] = (__bf16)b[1]; r[6] = (__bf16)b[2]; r[7] = (__bf16)b[3];
  return r;
}

// ---------------------------------------------------------------------------
// Kernel A (unchanged from R6): per (b, 64 k-rows): compute w[k], xv[k][c];
// write u pre-swizzled in mfma_16x16x32 B-fragment order, 9 tiles per t-step:
//   n<8: elem(b,t,n,lane,j) = w[k]*xv[k][n*16+np],  k = t*32+(lane>>4)*8+j
//   n=8: elem = (np==0) ? w[k] : 0    (denominator column)
// flat index (((b*64+t)*9+n)*64+lane)*8+j
// ---------------------------------------------------------------------------
__global__ __launch_bounds__(256) void prep_kernel(
    const float* __restrict__ x, const float* __restrict__ Wc,
    const float* __restrict__ Wcat, const float* __restrict__ Wx,
    const float* __restrict__ bx, __bf16* __restrict__ u)
{
  __shared__ __bf16 lds[9216];  // 18 KB: 2 t-steps x 9 tiles x 64 lanes x 8
  const int blk = blockIdx.x;            // 256 blocks
  const int b = blk >> 5, mt = blk & 31; // 32 blocks/batch, 64 rows each
  const int wv = threadIdx.x >> 6, lane = threadIdx.x & 63;
  const int np = lane & 15, G = lane >> 4;
  const int r0 = mt * 64 + wv * 16;      // wave's 16 k-rows

  const float* xp = x + ((size_t)(b * 2048 + r0 + np)) * 128 + G * 8;
  bf16x8 af[4];
#pragma unroll
  for (int kk = 0; kk < 4; ++kk) {
    f32x4 x0 = *(const f32x4*)(xp + kk * 32);
    f32x4 x1 = *(const f32x4*)(xp + kk * 32 + 4);
    af[kk] = cvt8(x0, x1);
  }

  f32x4 acc[8], accC;
#pragma unroll
  for (int n = 0; n < 8; ++n) { acc[n][0] = 0.f; acc[n][1] = 0.f; acc[n][2] = 0.f; acc[n][3] = 0.f; }
  accC[0] = accC[1] = accC[2] = accC[3] = 0.f;

#pragma unroll
  for (int n = 0; n < 8; ++n) {
    const float* wp = Wx + (n * 16 + np) * 128 + G * 8;
#pragma unroll
    for (int kk = 0; kk < 4; ++kk) {
      f32x4 w0 = *(const f32x4*)(wp + kk * 32);
      f32x4 w1 = *(const f32x4*)(wp + kk * 32 + 4);
      acc[n] = MFMA_BF16(af[kk], cvt8(w0, w1), acc[n]);
    }
  }
#pragma unroll
  for (int kk = 0; kk < 4; ++kk) {
    bf16x8 bf;
    if (np < 2) {
      const float* cp = Wc + np * 128 + kk * 32 + G * 8;
      f32x4 c0 = *(const f32x4*)cp;
      f32x4 c1 = *(const f32x4*)(cp + 4);
      bf = cvt8(c0, c1);
    } else {
#pragma unroll
      for (int j = 0; j < 8; ++j) bf[j] = (__bf16)0.0f;
    }
    accC = MFMA_BF16(af[kk], bf, accC);
  }

  const float a20 = Wcat[2], a21 = Wcat[3];
  float wexp[4];
#pragma unroll
  for (int r = 0; r < 4; ++r) {
    float c0 = __shfl(accC[r], lane & 48);
    float c1 = __shfl(accC[r], (lane & 48) | 1);
    c0 = c0 > 0.f ? c0 : 0.2f * c0;
    c1 = c1 > 0.f ? c1 : 0.2f * c1;
    wexp[r] = __expf(c0 * a20 + c1 * a21);
  }

  const int t_rel = wv >> 1;
  const int g_store = (wv & 1) * 2 + (G >> 1);
  const int j0 = (G & 1) * 4;
#pragma unroll
  for (int n = 0; n < 8; ++n) {
    float bxv = bx[n * 16 + np];
    bf16x4 v;
#pragma unroll
    for (int r = 0; r < 4; ++r) v[r] = (__bf16)(wexp[r] * (acc[n][r] + bxv));
    *(bf16x4*)(&lds[(t_rel * 9 + n) * 512 + g_store * 128 + np * 8 + j0]) = v;
  }
  {
    bf16x4 v8;
#pragma unroll
    for (int r = 0; r < 4; ++r) v8[r] = (np == 0) ? (__bf16)wexp[r] : (__bf16)0.0f;
    *(bf16x4*)(&lds[(t_rel * 9 + 8) * 512 + g_store * 128 + np * 8 + j0]) = v8;
  }
  __syncthreads();
  __bf16* dst = u + ((size_t)(b * 64 + mt * 2)) * 9 * 512;
  for (int s = threadIdx.x; s < 1152; s += 256)
    ((i32x4*)dst)[s] = ((const i32x4*)lds)[s];
}

// ---------------------------------------------------------------------------
// Kernel B v7: pure m97-shape K-loop — ALL global traffic via global_load_lds,
// ALL consumption via ds_read (lgkm domain). v6's bug: plain global u-loads
// inside the loop shared the FIFO vmcnt with in-flight staging -> every
// u-use drained the whole stage (~900cy) -> ~10k cy/iter. Now mask AND u are
// double-buffered in LDS.
//   BK=64 (2 t-steps), 32 iters. Per buffer: mask [32][64] i32 (8 KB,
//   XOR-swizzled via pre-swizzled global source) + u chunk (18 KB, linear
//   fragment order). 52 KB LDS total -> 2-3 blocks/CU.
// ---------------------------------------------------------------------------
__global__ __launch_bounds__(256) void attn_kernel(
    const int* __restrict__ mask, const __bf16* __restrict__ u,
    float* __restrict__ out)
{
  __shared__ char smem[2 * 26624];  // per buf: mask 8192 B + u 18432 B
  const int b = blockIdx.x & 7, rt = blockIdx.x >> 3;  // 8 x 64 (batch->XCD pin)
  const int wv = threadIdx.x >> 6, lane = threadIdx.x & 63;
  const int np = lane & 15, G = lane >> 4;
  const int row0 = rt * 32;
  const int n0 = wv * 2, n1 = n0 + 1;
  const int swzB = (np & 7) << 4;  // read-side swizzle (bytes)

  const char* gmask = (const char*)(mask + ((size_t)b * 2048 + row0) * 2048);
  const char* gu = (const char*)(u + (size_t)b * 64 * 9 * 512);

  // staging lane coords: mask instr i covers rows 4i..4i+3 of the tile;
  // this lane handles row 4i+G, bytes np*16 (dest) <- src byte np*16 ^ swz(row)
  const int mrow_g = G;                 // row within instr group
  const int mbyte = np * 16;

  f32x4 acc[2][3];
#pragma unroll
  for (int mi = 0; mi < 2; ++mi)
#pragma unroll
    for (int n = 0; n < 3; ++n) { acc[mi][n][0] = 0.f; acc[mi][n][1] = 0.f; acc[mi][n][2] = 0.f; acc[mi][n][3] = 0.f; }

#define STAGE(it, nb)                                                          \
  do {                                                                         \
    char* mb_ = smem + (nb) * 26624;                                           \
    char* ub_ = mb_ + 8192;                                                    \
    _Pragma("unroll")                                                          \
    for (int q = 0; q < 2; ++q) { /* mask: 8 KB, 2 instrs/wave */              \
      int i_ = wv * 2 + q;                                                     \
      int row_ = i_ * 4 + mrow_g;                                              \
      const char* gp = gmask + (size_t)row_ * 8192 + (it) * 256 +              \
                       (mbyte ^ ((row_ & 7) << 4));                            \
      GLOAD_LDS16(gp, mb_ + i_ * 1024);                                        \
    }                                                                          \
    for (int q = wv; q < 18; q += 4) { /* u: 18 KB linear, 4-5 instrs/wave */  \
      const char* gp = gu + (size_t)(it) * 18432 + q * 1024 + lane * 16;       \
      GLOAD_LDS16(gp, ub_ + q * 1024);                                         \
    }                                                                          \
  } while (0)

  STAGE(0, 0);
  __syncthreads();

  for (int it = 0; it < 32; ++it) {
    if (it < 31) STAGE(it + 1, (it + 1) & 1);
    const char* mb = smem + (it & 1) * 26624;
    const char* ub = mb + 8192;
#pragma unroll
    for (int tk = 0; tk < 2; ++tk) {
      bf16x8 U0 = *(const bf16x8*)(ub + tk * 9216 + n0 * 1024 + lane * 16);
      bf16x8 U1 = *(const bf16x8*)(ub + tk * 9216 + n1 * 1024 + lane * 16);
      bf16x8 UD = *(const bf16x8*)(ub + tk * 9216 + 8 * 1024 + lane * 16);
      const int Xb = (tk * 32 + G * 8) * 4;  // byte offset of this lane's 8 k
#pragma unroll
      for (int mi = 0; mi < 2; ++mi) {
        const char* rp = mb + (mi * 16 + np) * 256;
        i32x4 ma = *(const i32x4*)(rp + (Xb ^ swzB));
        i32x4 mz = *(const i32x4*)(rp + ((Xb + 16) ^ swzB));
        union { u32 w[4]; bf16x8 v; } A;
        A.w[0] = (ma[0] ? 0x3F80u : 0u) | (ma[1] ? 0x3F800000u : 0u);
        A.w[1] = (ma[2] ? 0x3F80u : 0u) | (ma[3] ? 0x3F800000u : 0u);
        A.w[2] = (mz[0] ? 0x3F80u : 0u) | (mz[1] ? 0x3F800000u : 0u);
        A.w[3] = (mz[2] ? 0x3F80u : 0u) | (mz[3] ? 0x3F800000u : 0u);
        acc[mi][0] = MFMA_BF16(A.v, U0, acc[mi][0]);
        acc[mi][1] = MFMA_BF16(A.v, U1, acc[mi][1]);
        acc[mi][2] = MFMA_BF16(A.v, UD, acc[mi][2]);
      }
    }
    __syncthreads();  // drains staged loads (vmcnt) + frees cur buffer
  }
#undef STAGE

  // epilogue: D row = mi*16 + 4G + r, cols n*16+np; denom = col0 of tile 8
#pragma unroll
  for (int mi = 0; mi < 2; ++mi) {
#pragma unroll
    for (int r = 0; r < 4; ++r) {
      float den = __shfl(acc[mi][2][r], lane & 48);
      float inv = 1.0f / den;
      float* op = out + ((size_t)b * 2048 + row0 + mi * 16 + 4 * G + r) * 128 + np;
      op[n0 * 16] = acc[mi][0][r] * inv;
      op[n1 * 16] = acc[mi][1][r] * inv;
    }
  }
}

extern "C" void kernel_launch(void* const* d_in, const int* in_sizes, int n_in,
                              void* d_out, int out_size, void* d_ws, size_t ws_size,
                              hipStream_t stream) {
  const float* x    = (const float*)d_in[0];
  const int*   mask = (const int*)d_in[1];
  // d_in[2] = Wr : unused (lr_row cancels in softmax over j)
  const float* Wc   = (const float*)d_in[3];
  const float* Wcat = (const float*)d_in[4];
  const float* Wx   = (const float*)d_in[5];
  const float* bx   = (const float*)d_in[6];
  float* out = (float*)d_out;

  // workspace: u = 8 b x 64 t x 9 tiles x 512 bf16 = 4.72 MB
  const size_t U_BYTES = (size_t)8 * 64 * 9 * 512 * 2;
  if (ws_size < U_BYTES) return;  // insufficient scratch
  __bf16* u = (__bf16*)d_ws;

  prep_kernel<<<256, 256, 0, stream>>>(x, Wc, Wcat, Wx, bx, u);
  attn_kernel<<<512, 256, 0, stream>>>(mask, u, out);
}